// Round 1
// baseline (1046.449 us; speedup 1.0000x reference)
//
#include <hip/hip_runtime.h>
#include <math.h>

#define NE 8
#define NH 2048
#define NI 1024
#define NT 512
#define NTOPK 2
#define NR 16
#define NGROUP 64
#define NPAIR (NT*NTOPK)   // 1024

__device__ const float NF4_TAB[16] = {
    -1.0f, -0.6961928009986877f, -0.5250730514526367f, -0.39491748809814453f,
    -0.28444138169288635f, -0.18477343022823334f, -0.09105003625154495f, 0.0f,
    0.07958029955625534f, 0.16093020141124725f, 0.24611230194568634f,
    0.33791524171829224f, 0.44070982933044434f, 0.5626170039176941f,
    0.7229568362236328f, 1.0f};

// ---------------- workspace layout (bytes) ----------------
#define OFF_EXPOFF 0         // int[16]
#define OFF_TOK    256       // int[1024]
#define OFF_EXP    4352      // int[1024]
#define OFF_W      8448      // float[1024]
#define OFF_XAG    12544     // float[1024*16]
#define OFF_XAU    78080     // float[1024*16]
#define OFF_HA     143616    // float[1024*16]
#define OFF_HBUF   209152    // float[1024*1024] (4 MB)

// -------- kernel 1: routing compaction (single block, 1024 threads) --------
__global__ __launch_bounds__(1024) void k_route(const int* __restrict__ idx,
                                                const float* __restrict__ w,
                                                int* expert_off, int* ptok,
                                                int* pexp, float* pw) {
    __shared__ int cnt[NE], off[NE + 1], cur[NE];
    int tid = threadIdx.x;            // 0..1023 == (t, slot)
    if (tid < NE) cnt[tid] = 0;
    __syncthreads();
    int e = idx[tid];
    float wt = w[tid];
    int t = tid >> 1;
    atomicAdd(&cnt[e], 1);
    __syncthreads();
    if (tid == 0) {
        off[0] = 0;
        for (int i = 0; i < NE; i++) off[i + 1] = off[i] + cnt[i];
    }
    __syncthreads();
    if (tid < NE) cur[tid] = off[tid];
    __syncthreads();
    int pos = atomicAdd(&cur[e], 1);
    ptok[pos] = t; pexp[pos] = e; pw[pos] = wt;
    if (tid <= NE) expert_off[tid] = off[tid];
}

// -------- kernel 2: xA_g[p][r], xA_u[p][r] (rank-16 projections) --------
__global__ __launch_bounds__(256) void k_xA(const float* __restrict__ x,
                                            const float* __restrict__ gA,
                                            const float* __restrict__ uA,
                                            const int* __restrict__ ptok,
                                            const int* __restrict__ pexp,
                                            float* __restrict__ xAg,
                                            float* __restrict__ xAu) {
    int p = blockIdx.x;
    int t = ptok[p], e = pexp[p];
    int tid = threadIdx.x;
    int r = tid & 15, ch = tid >> 4;          // 16 chunks of 128
    const float* xr = x + (size_t)t * NH;
    const float* gAr = gA + (size_t)e * NH * NR;
    const float* uAr = uA + (size_t)e * NH * NR;
    float sg = 0.f, su = 0.f;
    for (int j = ch * 128; j < ch * 128 + 128; ++j) {
        float xv = xr[j];
        sg += xv * gAr[j * NR + r];
        su += xv * uAr[j * NR + r];
    }
    __shared__ float red[2][16][16];
    red[0][ch][r] = sg; red[1][ch][r] = su;
    __syncthreads();
    for (int st = 8; st >= 1; st >>= 1) {
        if (ch < st) {
            red[0][ch][r] += red[0][ch + st][r];
            red[1][ch][r] += red[1][ch + st][r];
        }
        __syncthreads();
    }
    if (tid < 16) {
        xAg[p * NR + tid] = red[0][0][tid];
        xAu[p * NR + tid] = red[1][0][tid];
    }
}

// -------- kernel 3: gate/up grouped GEMM + LoRA + SiLU -> h_buf --------
__global__ __launch_bounds__(256) void k_gateup(
    const float* __restrict__ x, const int* __restrict__ gpk,
    const float* __restrict__ gsc, const int* __restrict__ upk,
    const float* __restrict__ usc, const float* __restrict__ gB,
    const float* __restrict__ uB, const int* __restrict__ expert_off,
    const int* __restrict__ ptok, const float* __restrict__ xAg,
    const float* __restrict__ xAu, float* __restrict__ hbuf) {
    __shared__ float cb[16];
    __shared__ __align__(16) float xt[16][17];
    __shared__ __align__(16) float wg[16][64];
    __shared__ __align__(16) float wu[16][64];
    __shared__ int tok[16];
    int tid = threadIdx.x;
    if (tid < 16) cb[tid] = NF4_TAB[tid];
    int e = blockIdx.x;
    int c0 = blockIdx.y * 64;
    int off = expert_off[e];
    int cnt = expert_off[e + 1] - off;
    int s = tid & 15, cbase = (tid >> 4) * 4;
    for (int s0 = blockIdx.z * 16; s0 < cnt; s0 += 16 * gridDim.z) {
        if (tid < 16) tok[tid] = (s0 + tid < cnt) ? ptok[off + s0 + tid] : -1;
        __syncthreads();
        float ag[4] = {0, 0, 0, 0}, au[4] = {0, 0, 0, 0};
        for (int k0 = 0; k0 < NH; k0 += 16) {
            {   // x tile
                int ss = tid >> 4, kk = tid & 15;
                int tt = tok[ss];
                xt[ss][kk] = (tt >= 0) ? x[(size_t)tt * NH + k0 + kk] : 0.f;
            }
            int j0 = k0 >> 1;        // packed row base
            int srow = k0 >> 6;      // scale group row
            for (int q = tid; q < 512; q += 256) {
                int j = q >> 6, c = q & 63;
                int col = c0 + c;
                float sg = gsc[((size_t)e * (NH / NGROUP) + srow) * NI + col];
                int vg = gpk[((size_t)e * (NH / 2) + j0 + j) * NI + col];
                wg[2 * j][c] = cb[vg & 15] * sg;
                wg[2 * j + 1][c] = cb[(vg >> 4) & 15] * sg;
                float su = usc[((size_t)e * (NH / NGROUP) + srow) * NI + col];
                int vu = upk[((size_t)e * (NH / 2) + j0 + j) * NI + col];
                wu[2 * j][c] = cb[vu & 15] * su;
                wu[2 * j + 1][c] = cb[(vu >> 4) & 15] * su;
            }
            __syncthreads();
#pragma unroll
            for (int kk = 0; kk < 16; ++kk) {
                float xv = xt[s][kk];
                float4 g4 = *(const float4*)&wg[kk][cbase];
                float4 u4 = *(const float4*)&wu[kk][cbase];
                ag[0] += xv * g4.x; ag[1] += xv * g4.y;
                ag[2] += xv * g4.z; ag[3] += xv * g4.w;
                au[0] += xv * u4.x; au[1] += xv * u4.y;
                au[2] += xv * u4.z; au[3] += xv * u4.w;
            }
            __syncthreads();
        }
        if (s0 + s < cnt) {
            int p = off + s0 + s;
#pragma unroll
            for (int r = 0; r < NR; ++r) {
                float agr = xAg[p * NR + r], aur = xAu[p * NR + r];
                const float* gBr = gB + ((size_t)e * NR + r) * NI + c0 + cbase;
                const float* uBr = uB + ((size_t)e * NR + r) * NI + c0 + cbase;
#pragma unroll
                for (int jj = 0; jj < 4; jj++) {
                    ag[jj] += agr * gBr[jj];
                    au[jj] += aur * uBr[jj];
                }
            }
            float4 hv;
#pragma unroll
            for (int jj = 0; jj < 4; jj++) {
                float g = ag[jj], u = au[jj];
                float sig = 1.f / (1.f + expf(-g));
                ((float*)&hv)[jj] = g * sig * u;
            }
            *(float4*)(hbuf + (size_t)p * NI + c0 + cbase) = hv;
        }
        __syncthreads();
    }
}

// -------- kernel 4: hA[p][r] = h . down_A --------
__global__ __launch_bounds__(256) void k_hA(const float* __restrict__ hbuf,
                                            const float* __restrict__ dA,
                                            const int* __restrict__ pexp,
                                            float* __restrict__ hA) {
    int p = blockIdx.x;
    int e = pexp[p];
    int tid = threadIdx.x;
    int r = tid & 15, ch = tid >> 4;   // 16 chunks of 64
    const float* hr = hbuf + (size_t)p * NI;
    const float* dAr = dA + (size_t)e * NI * NR;
    float sv = 0.f;
    for (int j = ch * 64; j < ch * 64 + 64; ++j)
        sv += hr[j] * dAr[j * NR + r];
    __shared__ float red[16][16];
    red[ch][r] = sv;
    __syncthreads();
    for (int st = 8; st >= 1; st >>= 1) {
        if (ch < st) red[ch][r] += red[ch + st][r];
        __syncthreads();
    }
    if (tid < 16) hA[p * NR + tid] = red[0][tid];
}

// -------- kernel 5: down GEMM + LoRA + routed combine --------
__global__ __launch_bounds__(256) void k_down(
    const float* __restrict__ hbuf, const int* __restrict__ dpk,
    const float* __restrict__ dsc, const float* __restrict__ dB,
    const int* __restrict__ expert_off, const int* __restrict__ ptok,
    const float* __restrict__ pw, const float* __restrict__ hA,
    float* __restrict__ out) {
    __shared__ float cb[16];
    __shared__ __align__(16) float ht[16][17];
    __shared__ __align__(16) float wd[16][64];
    int tid = threadIdx.x;
    if (tid < 16) cb[tid] = NF4_TAB[tid];
    int e = blockIdx.x;
    int c0 = blockIdx.y * 64;
    int off = expert_off[e];
    int cnt = expert_off[e + 1] - off;
    int s = tid & 15, cbase = (tid >> 4) * 4;
    for (int s0 = blockIdx.z * 16; s0 < cnt; s0 += 16 * gridDim.z) {
        float acc[4] = {0, 0, 0, 0};
        __syncthreads();
        for (int k0 = 0; k0 < NI; k0 += 16) {
            {   // h tile (compact rows)
                int ss = tid >> 4, kk = tid & 15;
                ht[ss][kk] = (s0 + ss < cnt)
                                 ? hbuf[(size_t)(off + s0 + ss) * NI + k0 + kk]
                                 : 0.f;
            }
            int j0 = k0 >> 1;
            int srow = k0 >> 6;
            for (int q = tid; q < 512; q += 256) {
                int j = q >> 6, c = q & 63;
                int col = c0 + c;
                float sd = dsc[((size_t)e * (NI / NGROUP) + srow) * NH + col];
                int vd = dpk[((size_t)e * (NI / 2) + j0 + j) * NH + col];
                wd[2 * j][c] = cb[vd & 15] * sd;
                wd[2 * j + 1][c] = cb[(vd >> 4) & 15] * sd;
            }
            __syncthreads();
#pragma unroll
            for (int kk = 0; kk < 16; ++kk) {
                float hv = ht[s][kk];
                float4 d4 = *(const float4*)&wd[kk][cbase];
                acc[0] += hv * d4.x; acc[1] += hv * d4.y;
                acc[2] += hv * d4.z; acc[3] += hv * d4.w;
            }
            __syncthreads();
        }
        if (s0 + s < cnt) {
            int p = off + s0 + s;
#pragma unroll
            for (int r = 0; r < NR; ++r) {
                float ar = hA[p * NR + r];
                const float* dBr = dB + ((size_t)e * NR + r) * NH + c0 + cbase;
#pragma unroll
                for (int jj = 0; jj < 4; jj++) acc[jj] += ar * dBr[jj];
            }
            float wt = pw[p];
            int t = ptok[p];
            float* op = out + (size_t)t * NH + c0 + cbase;
#pragma unroll
            for (int jj = 0; jj < 4; jj++) atomicAdd(&op[jj], wt * acc[jj]);
        }
    }
}

extern "C" void kernel_launch(void* const* d_in, const int* in_sizes, int n_in,
                              void* d_out, int out_size, void* d_ws,
                              size_t ws_size, hipStream_t stream) {
    const float* x = (const float*)d_in[0];
    const int* topk_idx = (const int*)d_in[1];
    const float* topk_w = (const float*)d_in[2];
    const int* gate_packed = (const int*)d_in[3];
    const float* gate_scales = (const float*)d_in[4];
    const int* up_packed = (const int*)d_in[5];
    const float* up_scales = (const float*)d_in[6];
    const int* down_packed = (const int*)d_in[7];
    const float* down_scales = (const float*)d_in[8];
    const float* gate_A = (const float*)d_in[9];
    const float* gate_B = (const float*)d_in[10];
    const float* up_A = (const float*)d_in[11];
    const float* up_B = (const float*)d_in[12];
    const float* down_A = (const float*)d_in[13];
    const float* down_B = (const float*)d_in[14];
    float* out = (float*)d_out;

    char* ws = (char*)d_ws;
    int* expert_off = (int*)(ws + OFF_EXPOFF);
    int* ptok = (int*)(ws + OFF_TOK);
    int* pexp = (int*)(ws + OFF_EXP);
    float* pw = (float*)(ws + OFF_W);
    float* xAg = (float*)(ws + OFF_XAG);
    float* xAu = (float*)(ws + OFF_XAU);
    float* hA = (float*)(ws + OFF_HA);
    float* hbuf = (float*)(ws + OFF_HBUF);

    hipMemsetAsync(d_out, 0, (size_t)NT * NH * sizeof(float), stream);

    k_route<<<1, 1024, 0, stream>>>(topk_idx, topk_w, expert_off, ptok, pexp, pw);
    k_xA<<<NPAIR, 256, 0, stream>>>(x, gate_A, up_A, ptok, pexp, xAg, xAu);
    k_gateup<<<dim3(NE, NI / 64, 8), 256, 0, stream>>>(
        x, gate_packed, gate_scales, up_packed, up_scales, gate_B, up_B,
        expert_off, ptok, xAg, xAu, hbuf);
    k_hA<<<NPAIR, 256, 0, stream>>>(hbuf, down_A, pexp, hA);
    k_down<<<dim3(NE, NH / 64, 8), 256, 0, stream>>>(
        hbuf, down_packed, down_scales, down_B, expert_off, ptok, pw, hA, out);
}

// Round 2
// 486.049 us; speedup vs baseline: 2.1530x; 2.1530x over previous
//
#include <hip/hip_runtime.h>
#include <math.h>

#define NE 8
#define NH 2048
#define NI 1024
#define NT 512
#define NTOPK 2
#define NR 16
#define NGROUP 64
#define NPAIR (NT*NTOPK)   // 1024

typedef short bf16x8 __attribute__((ext_vector_type(8)));
typedef float f32x16 __attribute__((ext_vector_type(16)));
typedef unsigned int uint;

#define MFMA32 __builtin_amdgcn_mfma_f32_32x32x16_bf16

__device__ const float NF4_TAB[16] = {
    -1.0f, -0.6961928009986877f, -0.5250730514526367f, -0.39491748809814453f,
    -0.28444138169288635f, -0.18477343022823334f, -0.09105003625154495f, 0.0f,
    0.07958029955625534f, 0.16093020141124725f, 0.24611230194568634f,
    0.33791524171829224f, 0.44070982933044434f, 0.5626170039176941f,
    0.7229568362236328f, 1.0f};

// ---------------- workspace layout (bytes) ----------------
#define OFF_EXPOFF 0         // int[16]
#define OFF_TOK    256       // int[1024]
#define OFF_EXP    4352      // int[1024]
#define OFF_W      8448      // float[1024]
#define OFF_XAG    12544     // ushort[1024*16] bf16
#define OFF_XAU    45312     // ushort[1024*16]
#define OFF_HA     78080     // ushort[1024*16]
#define OFF_XB     131072    // ushort[512*2048] bf16 x (2 MB)
#define OFF_HBUF   2228224   // ushort[1024*1024] bf16 h (2 MB)

__device__ inline uint f2bf(float f) {                 // round-half-up bf16 (low 16)
    return (__float_as_uint(f) + 0x8000u) >> 16;
}
__device__ inline uint bfpack2(float a, float b) {     // two bf16 packed in a dword
    return ((__float_as_uint(a) + 0x8000u) >> 16) |
           ((__float_as_uint(b) + 0x8000u) & 0xFFFF0000u);
}
__device__ inline bf16x8 asbf(uint4 w) {
    union { uint4 u; bf16x8 b; } c; c.u = w; return c.b;
}
__device__ inline bf16x8 bfzero() { return asbf(make_uint4(0,0,0,0)); }

// -------- kernel 1: routing compaction (single block, 1024 threads) --------
__global__ __launch_bounds__(1024) void k_route(const int* __restrict__ idx,
                                                const float* __restrict__ w,
                                                int* expert_off, int* ptok,
                                                int* pexp, float* pw) {
    __shared__ int cnt[NE], off[NE + 1], cur[NE];
    int tid = threadIdx.x;            // 0..1023 == (t, slot)
    if (tid < NE) cnt[tid] = 0;
    __syncthreads();
    int e = idx[tid];
    float wt = w[tid];
    int t = tid >> 1;
    atomicAdd(&cnt[e], 1);
    __syncthreads();
    if (tid == 0) {
        off[0] = 0;
        for (int i = 0; i < NE; i++) off[i + 1] = off[i] + cnt[i];
    }
    __syncthreads();
    if (tid < NE) cur[tid] = off[tid];
    __syncthreads();
    int pos = atomicAdd(&cur[e], 1);
    ptok[pos] = t; pexp[pos] = e; pw[pos] = wt;
    if (tid <= NE) expert_off[tid] = off[tid];
}

// -------- kernel 2: x fp32 -> bf16 --------
__global__ __launch_bounds__(256) void k_xcvt(const float* __restrict__ x,
                                              unsigned short* __restrict__ xb) {
    int i = (blockIdx.x * 256 + threadIdx.x) * 8;
    float4 v0 = *(const float4*)(x + i);
    float4 v1 = *(const float4*)(x + i + 4);
    uint4 w;
    w.x = bfpack2(v0.x, v0.y); w.y = bfpack2(v0.z, v0.w);
    w.z = bfpack2(v1.x, v1.y); w.w = bfpack2(v1.z, v1.w);
    *(uint4*)(xb + i) = w;
}

// -------- kernel 3: xA_g[p][r], xA_u[p][r] (rank-16 projections, bf16 out) ----
__global__ __launch_bounds__(256) void k_xA(const float* __restrict__ x,
                                            const float* __restrict__ gA,
                                            const float* __restrict__ uA,
                                            const int* __restrict__ ptok,
                                            const int* __restrict__ pexp,
                                            unsigned short* __restrict__ xAg,
                                            unsigned short* __restrict__ xAu) {
    int p = blockIdx.x;
    int t = ptok[p], e = pexp[p];
    int tid = threadIdx.x;
    int r = tid & 15, ch = tid >> 4;          // 16 chunks of 128
    const float* xr = x + (size_t)t * NH;
    const float* gAr = gA + (size_t)e * NH * NR;
    const float* uAr = uA + (size_t)e * NH * NR;
    float sg = 0.f, su = 0.f;
    for (int j = ch * 128; j < ch * 128 + 128; ++j) {
        float xv = xr[j];
        sg += xv * gAr[j * NR + r];
        su += xv * uAr[j * NR + r];
    }
    __shared__ float red[2][16][16];
    red[0][ch][r] = sg; red[1][ch][r] = su;
    __syncthreads();
    for (int st = 8; st >= 1; st >>= 1) {
        if (ch < st) {
            red[0][ch][r] += red[0][ch + st][r];
            red[1][ch][r] += red[1][ch + st][r];
        }
        __syncthreads();
    }
    if (tid < 16) {
        xAg[p * NR + tid] = (unsigned short)f2bf(red[0][0][tid]);
        xAu[p * NR + tid] = (unsigned short)f2bf(red[1][0][tid]);
    }
}

// -------- kernel 4: gate/up grouped GEMM (MFMA, 1 wave/block, no barriers) ---
// wave tile: 64 rows (pairs) x 32 cols, both gate and up. LoRA via K=16 ext MFMA.
__global__ __launch_bounds__(64) void k_gateup_mfma(
    const unsigned short* __restrict__ xb,
    const int* __restrict__ gpk, const float* __restrict__ gsc,
    const int* __restrict__ upk, const float* __restrict__ usc,
    const float* __restrict__ gB, const float* __restrict__ uB,
    const unsigned short* __restrict__ xAg, const unsigned short* __restrict__ xAu,
    const int* __restrict__ expert_off, const int* __restrict__ ptok,
    unsigned short* __restrict__ hbuf)
{
    __shared__ float2 ptab[256];
    int lane = threadIdx.x;
    for (int i = lane; i < 256; i += 64)
        ptab[i] = make_float2(NF4_TAB[i & 15], NF4_TAB[(i >> 4) & 15]);
    __syncthreads();

    int e = blockIdx.x;
    int c0 = blockIdx.y * 32;
    int off = expert_off[e];
    int cnt = expert_off[e + 1] - off;
    int col = c0 + (lane & 31);
    int q = lane >> 5;

    const size_t pkbase = (size_t)e * (NH / 2) * NI + col;
    const size_t scbase = (size_t)e * (NH / NGROUP) * NI + col;

    for (int s0 = blockIdx.z * 64; s0 < cnt; s0 += 128) {
        int r0 = s0 + (lane & 31), r1 = r0 + 32;
        int tk0 = (r0 < cnt) ? ptok[off + r0] : -1;
        int tk1 = (r1 < cnt) ? ptok[off + r1] : -1;
        const unsigned short* xp0 = xb + (size_t)tk0 * NH;
        const unsigned short* xp1 = xb + (size_t)tk1 * NH;

        f32x16 accg[2], accu[2];
        #pragma unroll
        for (int i = 0; i < 16; ++i) {
            accg[0][i] = 0.f; accg[1][i] = 0.f;
            accu[0][i] = 0.f; accu[1][i] = 0.f;
        }

        for (int k0 = 0; k0 < NH; k0 += 32) {
            float scg = gsc[scbase + (size_t)(k0 >> 6) * NI];
            float scu = usc[scbase + (size_t)(k0 >> 6) * NI];
            const int* gp = gpk + pkbase + (size_t)(k0 >> 1) * NI;
            const int* up = upk + pkbase + (size_t)(k0 >> 1) * NI;
            #pragma unroll
            for (int s = 0; s < 2; ++s) {
                int kk = k0 + s * 16 + q * 8;
                bf16x8 a0 = (tk0 >= 0) ? *(const bf16x8*)(xp0 + kk) : bfzero();
                bf16x8 a1 = (tk1 >= 0) ? *(const bf16x8*)(xp1 + kk) : bfzero();
                int rr = (s * 8 + q * 4) * NI;
                uint4 wg4, wu4;
                uint* wg = &wg4.x; uint* wu = &wu4.x;
                #pragma unroll
                for (int i = 0; i < 4; ++i) {
                    int vg = gp[rr + i * NI] & 255;
                    int vu = up[rr + i * NI] & 255;
                    float2 pg = ptab[vg];
                    float2 pu = ptab[vu];
                    wg[i] = bfpack2(pg.x * scg, pg.y * scg);
                    wu[i] = bfpack2(pu.x * scu, pu.y * scu);
                }
                bf16x8 bg = asbf(wg4), bu = asbf(wu4);
                accg[0] = MFMA32(a0, bg, accg[0], 0, 0, 0);
                accg[1] = MFMA32(a1, bg, accg[1], 0, 0, 0);
                accu[0] = MFMA32(a0, bu, accu[0], 0, 0, 0);
                accu[1] = MFMA32(a1, bu, accu[1], 0, 0, 0);
            }
        }
        // LoRA extension: += (x.A) . B  (K = 16)
        {
            bf16x8 z = bfzero();
            bf16x8 ag0 = (r0 < cnt) ? *(const bf16x8*)(xAg + (size_t)(off + r0) * NR + q * 8) : z;
            bf16x8 ag1 = (r1 < cnt) ? *(const bf16x8*)(xAg + (size_t)(off + r1) * NR + q * 8) : z;
            bf16x8 au0 = (r0 < cnt) ? *(const bf16x8*)(xAu + (size_t)(off + r0) * NR + q * 8) : z;
            bf16x8 au1 = (r1 < cnt) ? *(const bf16x8*)(xAu + (size_t)(off + r1) * NR + q * 8) : z;
            const float* gq = gB + ((size_t)e * NR + q * 8) * NI + col;
            const float* uq = uB + ((size_t)e * NR + q * 8) * NI + col;
            uint4 wg4, wu4;
            uint* wg = &wg4.x; uint* wu = &wu4.x;
            #pragma unroll
            for (int i = 0; i < 4; ++i) {
                wg[i] = bfpack2(gq[(2 * i) * NI], gq[(2 * i + 1) * NI]);
                wu[i] = bfpack2(uq[(2 * i) * NI], uq[(2 * i + 1) * NI]);
            }
            bf16x8 bg = asbf(wg4), bu = asbf(wu4);
            accg[0] = MFMA32(ag0, bg, accg[0], 0, 0, 0);
            accg[1] = MFMA32(ag1, bg, accg[1], 0, 0, 0);
            accu[0] = MFMA32(au0, bu, accu[0], 0, 0, 0);
            accu[1] = MFMA32(au1, bu, accu[1], 0, 0, 0);
        }
        // epilogue: SiLU(g)*u -> hbuf (bf16)
        int rb = 4 * q;
        #pragma unroll
        for (int mi = 0; mi < 2; ++mi) {
            #pragma unroll
            for (int reg = 0; reg < 16; ++reg) {
                int rloc = mi * 32 + rb + (reg & 3) + 8 * (reg >> 2);
                if (s0 + rloc < cnt) {
                    float g = accg[mi][reg], u = accu[mi][reg];
                    float h = g * u / (1.f + __expf(-g));
                    hbuf[(size_t)(off + s0 + rloc) * NI + col] = (unsigned short)f2bf(h);
                }
            }
        }
    }
}

// -------- kernel 5: hA[p][r] = h . down_A (bf16 h in, bf16 out) --------
__global__ __launch_bounds__(256) void k_hA(const unsigned short* __restrict__ hbuf,
                                            const float* __restrict__ dA,
                                            const int* __restrict__ pexp,
                                            unsigned short* __restrict__ hA) {
    int p = blockIdx.x;
    int e = pexp[p];
    int tid = threadIdx.x;
    int r = tid & 15, ch = tid >> 4;   // 16 chunks of 64
    const unsigned short* hr = hbuf + (size_t)p * NI;
    const float* dAr = dA + (size_t)e * NI * NR;
    float sv = 0.f;
    for (int j = ch * 64; j < ch * 64 + 64; ++j) {
        float hv = __uint_as_float((uint)hr[j] << 16);
        sv += hv * dAr[j * NR + r];
    }
    __shared__ float red[16][16];
    red[ch][r] = sv;
    __syncthreads();
    for (int st = 8; st >= 1; st >>= 1) {
        if (ch < st) red[ch][r] += red[ch + st][r];
        __syncthreads();
    }
    if (tid < 16) hA[p * NR + tid] = (unsigned short)f2bf(red[0][tid]);
}

// -------- kernel 6: down GEMM (MFMA) + LoRA ext + routed atomic combine ------
__global__ __launch_bounds__(64) void k_down_mfma(
    const unsigned short* __restrict__ hbuf,
    const int* __restrict__ dpk, const float* __restrict__ dsc,
    const float* __restrict__ dB,
    const unsigned short* __restrict__ hA,
    const int* __restrict__ expert_off, const int* __restrict__ ptok,
    const float* __restrict__ pw,
    float* __restrict__ out)
{
    __shared__ float2 ptab[256];
    int lane = threadIdx.x;
    for (int i = lane; i < 256; i += 64)
        ptab[i] = make_float2(NF4_TAB[i & 15], NF4_TAB[(i >> 4) & 15]);
    __syncthreads();

    int e = blockIdx.x;
    int c0 = blockIdx.y * 32;
    int off = expert_off[e];
    int cnt = expert_off[e + 1] - off;
    int col = c0 + (lane & 31);
    int q = lane >> 5;

    const size_t pkbase = (size_t)e * (NI / 2) * NH + col;
    const size_t scbase = (size_t)e * (NI / NGROUP) * NH + col;

    for (int s0 = blockIdx.z * 64; s0 < cnt; s0 += 128) {
        int r0 = s0 + (lane & 31), r1 = r0 + 32;
        bool v0 = r0 < cnt, v1 = r1 < cnt;
        const unsigned short* hp0 = hbuf + (size_t)(off + r0) * NI;
        const unsigned short* hp1 = hbuf + (size_t)(off + r1) * NI;

        f32x16 acc[2];
        #pragma unroll
        for (int i = 0; i < 16; ++i) { acc[0][i] = 0.f; acc[1][i] = 0.f; }

        for (int k0 = 0; k0 < NI; k0 += 32) {
            float sc = dsc[scbase + (size_t)(k0 >> 6) * NH];
            const int* dp = dpk + pkbase + (size_t)(k0 >> 1) * NH;
            #pragma unroll
            for (int s = 0; s < 2; ++s) {
                int kk = k0 + s * 16 + q * 8;
                bf16x8 a0 = v0 ? *(const bf16x8*)(hp0 + kk) : bfzero();
                bf16x8 a1 = v1 ? *(const bf16x8*)(hp1 + kk) : bfzero();
                int rr = (s * 8 + q * 4) * NH;
                uint4 w4;
                uint* w = &w4.x;
                #pragma unroll
                for (int i = 0; i < 4; ++i) {
                    int v = dp[rr + i * NH] & 255;
                    float2 pv = ptab[v];
                    w[i] = bfpack2(pv.x * sc, pv.y * sc);
                }
                bf16x8 b = asbf(w4);
                acc[0] = MFMA32(a0, b, acc[0], 0, 0, 0);
                acc[1] = MFMA32(a1, b, acc[1], 0, 0, 0);
            }
        }
        // LoRA extension: += (h.down_A) . down_B (K = 16)
        {
            bf16x8 z = bfzero();
            bf16x8 a0 = v0 ? *(const bf16x8*)(hA + (size_t)(off + r0) * NR + q * 8) : z;
            bf16x8 a1 = v1 ? *(const bf16x8*)(hA + (size_t)(off + r1) * NR + q * 8) : z;
            const float* dq_ = dB + ((size_t)e * NR + q * 8) * NH + col;
            uint4 w4;
            uint* w = &w4.x;
            #pragma unroll
            for (int i = 0; i < 4; ++i)
                w[i] = bfpack2(dq_[(2 * i) * NH], dq_[(2 * i + 1) * NH]);
            bf16x8 b = asbf(w4);
            acc[0] = MFMA32(a0, b, acc[0], 0, 0, 0);
            acc[1] = MFMA32(a1, b, acc[1], 0, 0, 0);
        }
        // epilogue: weighted atomic combine into out
        int rb = 4 * q;
        #pragma unroll
        for (int mi = 0; mi < 2; ++mi) {
            #pragma unroll
            for (int reg = 0; reg < 16; ++reg) {
                int rloc = mi * 32 + rb + (reg & 3) + 8 * (reg >> 2);
                if (s0 + rloc < cnt) {
                    int p = off + s0 + rloc;
                    float v = acc[mi][reg] * pw[p];
                    atomicAdd(&out[(size_t)ptok[p] * NH + col], v);
                }
            }
        }
    }
}

extern "C" void kernel_launch(void* const* d_in, const int* in_sizes, int n_in,
                              void* d_out, int out_size, void* d_ws,
                              size_t ws_size, hipStream_t stream) {
    const float* x = (const float*)d_in[0];
    const int* topk_idx = (const int*)d_in[1];
    const float* topk_w = (const float*)d_in[2];
    const int* gate_packed = (const int*)d_in[3];
    const float* gate_scales = (const float*)d_in[4];
    const int* up_packed = (const int*)d_in[5];
    const float* up_scales = (const float*)d_in[6];
    const int* down_packed = (const int*)d_in[7];
    const float* down_scales = (const float*)d_in[8];
    const float* gate_A = (const float*)d_in[9];
    const float* gate_B = (const float*)d_in[10];
    const float* up_A = (const float*)d_in[11];
    const float* up_B = (const float*)d_in[12];
    const float* down_A = (const float*)d_in[13];
    const float* down_B = (const float*)d_in[14];
    float* out = (float*)d_out;

    char* ws = (char*)d_ws;
    int* expert_off = (int*)(ws + OFF_EXPOFF);
    int* ptok = (int*)(ws + OFF_TOK);
    int* pexp = (int*)(ws + OFF_EXP);
    float* pw = (float*)(ws + OFF_W);
    unsigned short* xAg = (unsigned short*)(ws + OFF_XAG);
    unsigned short* xAu = (unsigned short*)(ws + OFF_XAU);
    unsigned short* hA = (unsigned short*)(ws + OFF_HA);
    unsigned short* xb = (unsigned short*)(ws + OFF_XB);
    unsigned short* hbuf = (unsigned short*)(ws + OFF_HBUF);

    hipMemsetAsync(d_out, 0, (size_t)NT * NH * sizeof(float), stream);

    k_route<<<1, 1024, 0, stream>>>(topk_idx, topk_w, expert_off, ptok, pexp, pw);
    k_xcvt<<<(NT * NH) / (256 * 8), 256, 0, stream>>>(x, xb);
    k_xA<<<NPAIR, 256, 0, stream>>>(x, gate_A, up_A, ptok, pexp, xAg, xAu);
    k_gateup_mfma<<<dim3(NE, NI / 32, 2), 64, 0, stream>>>(
        xb, gate_packed, gate_scales, up_packed, up_scales, gate_B, up_B,
        xAg, xAu, expert_off, ptok, hbuf);
    k_hA<<<NPAIR, 256, 0, stream>>>(hbuf, down_A, pexp, hA);
    k_down_mfma<<<dim3(NE, NH / 32, 2), 64, 0, stream>>>(
        hbuf, down_packed, down_scales, down_B, hA, expert_off, ptok, pw, out);
}

// Round 3
// 328.980 us; speedup vs baseline: 3.1809x; 1.4774x over previous
//
#include <hip/hip_runtime.h>
#include <math.h>

#define NE 8
#define NH 2048
#define NI 1024
#define NT 512
#define NTOPK 2
#define NR 16
#define NGROUP 64
#define NPAIR (NT*NTOPK)   // 1024

typedef short bf16x8 __attribute__((ext_vector_type(8)));
typedef float f32x16 __attribute__((ext_vector_type(16)));
typedef unsigned int uint;

#define MFMA32 __builtin_amdgcn_mfma_f32_32x32x16_bf16

__device__ const float NF4_TAB[16] = {
    -1.0f, -0.6961928009986877f, -0.5250730514526367f, -0.39491748809814453f,
    -0.28444138169288635f, -0.18477343022823334f, -0.09105003625154495f, 0.0f,
    0.07958029955625534f, 0.16093020141124725f, 0.24611230194568634f,
    0.33791524171829224f, 0.44070982933044434f, 0.5626170039176941f,
    0.7229568362236328f, 1.0f};

// ---------------- workspace layout (bytes) ----------------
#define OFF_EXPOFF 0         // int[16]
#define OFF_TOK    256       // int[1024]
#define OFF_EXP    4352      // int[1024]
#define OFF_W      8448      // float[1024]
#define OFF_XAG    12544     // ushort[1024*16] bf16
#define OFF_XAU    45312     // ushort[1024*16]
#define OFF_HA     78080     // ushort[1024*16]
#define OFF_XB     131072    // ushort[512*2048] bf16 x (2 MB)
#define OFF_HBUF   2228224   // ushort[1024*1024] bf16 h (2 MB)

__device__ inline uint f2bf(float f) {                 // round-half-up bf16 (low 16)
    return (__float_as_uint(f) + 0x8000u) >> 16;
}
__device__ inline uint bfpack2(float a, float b) {     // two bf16 packed in a dword
    return ((__float_as_uint(a) + 0x8000u) >> 16) |
           ((__float_as_uint(b) + 0x8000u) & 0xFFFF0000u);
}
__device__ inline bf16x8 asbf(uint4 w) {
    union { uint4 u; bf16x8 b; } c; c.u = w; return c.b;
}
__device__ inline bf16x8 bfzero() { return asbf(make_uint4(0,0,0,0)); }

// -------- kernel 1: routing compaction (single block, 1024 threads) --------
__global__ __launch_bounds__(1024) void k_route(const int* __restrict__ idx,
                                                const float* __restrict__ w,
                                                int* expert_off, int* ptok,
                                                int* pexp, float* pw) {
    __shared__ int cnt[NE], off[NE + 1], cur[NE];
    int tid = threadIdx.x;            // 0..1023 == (t, slot)
    if (tid < NE) cnt[tid] = 0;
    __syncthreads();
    int e = idx[tid];
    float wt = w[tid];
    int t = tid >> 1;
    atomicAdd(&cnt[e], 1);
    __syncthreads();
    if (tid == 0) {
        off[0] = 0;
        for (int i = 0; i < NE; i++) off[i + 1] = off[i] + cnt[i];
    }
    __syncthreads();
    if (tid < NE) cur[tid] = off[tid];
    __syncthreads();
    int pos = atomicAdd(&cur[e], 1);
    ptok[pos] = t; pexp[pos] = e; pw[pos] = wt;
    if (tid <= NE) expert_off[tid] = off[tid];
}

// -------- kernel 2: x fp32 -> bf16 --------
__global__ __launch_bounds__(256) void k_xcvt(const float* __restrict__ x,
                                              unsigned short* __restrict__ xb) {
    int i = (blockIdx.x * 256 + threadIdx.x) * 8;
    float4 v0 = *(const float4*)(x + i);
    float4 v1 = *(const float4*)(x + i + 4);
    uint4 w;
    w.x = bfpack2(v0.x, v0.y); w.y = bfpack2(v0.z, v0.w);
    w.z = bfpack2(v1.x, v1.y); w.w = bfpack2(v1.z, v1.w);
    *(uint4*)(xb + i) = w;
}

// -------- kernel 3: xA_g[p][r], xA_u[p][r] (rank-16 projections, bf16 out) ----
__global__ __launch_bounds__(256) void k_xA(const float* __restrict__ x,
                                            const float* __restrict__ gA,
                                            const float* __restrict__ uA,
                                            const int* __restrict__ ptok,
                                            const int* __restrict__ pexp,
                                            unsigned short* __restrict__ xAg,
                                            unsigned short* __restrict__ xAu) {
    int p = blockIdx.x;
    int t = ptok[p], e = pexp[p];
    int tid = threadIdx.x;
    int r = tid & 15, ch = tid >> 4;          // 16 chunks of 128
    const float* xr = x + (size_t)t * NH;
    const float* gAr = gA + (size_t)e * NH * NR;
    const float* uAr = uA + (size_t)e * NH * NR;
    float sg = 0.f, su = 0.f;
    for (int j = ch * 128; j < ch * 128 + 128; ++j) {
        float xv = xr[j];
        sg += xv * gAr[j * NR + r];
        su += xv * uAr[j * NR + r];
    }
    __shared__ float red[2][16][16];
    red[0][ch][r] = sg; red[1][ch][r] = su;
    __syncthreads();
    for (int st = 8; st >= 1; st >>= 1) {
        if (ch < st) {
            red[0][ch][r] += red[0][ch + st][r];
            red[1][ch][r] += red[1][ch + st][r];
        }
        __syncthreads();
    }
    if (tid < 16) {
        xAg[p * NR + tid] = (unsigned short)f2bf(red[0][0][tid]);
        xAu[p * NR + tid] = (unsigned short)f2bf(red[1][0][tid]);
    }
}

// -------- kernel 4: gate/up grouped GEMM, 4-wave K-split + LDS reduce --------
// block = 256 thr (4 waves). tile: 64 rows x 32 cols, each wave K=512.
// register double-buffer prefetch; wave 0 adds LoRA ext + reduces + SiLU.
__global__ __launch_bounds__(256) void k_gateup_mfma(
    const unsigned short* __restrict__ xb,
    const int* __restrict__ gpk, const float* __restrict__ gsc,
    const int* __restrict__ upk, const float* __restrict__ usc,
    const float* __restrict__ gB, const float* __restrict__ uB,
    const unsigned short* __restrict__ xAg, const unsigned short* __restrict__ xAu,
    const int* __restrict__ expert_off, const int* __restrict__ ptok,
    unsigned short* __restrict__ hbuf)
{
    __shared__ float2 ptab[256];
    __shared__ float red[3][2][2][16][64];   // [wv-1][mat][mi][reg][lane]
    int tid = threadIdx.x;
    int lane = tid & 63;
    int wv = tid >> 6;                       // K-split 0..3
    for (int i = tid; i < 256; i += 256)
        ptab[i] = make_float2(NF4_TAB[i & 15], NF4_TAB[(i >> 4) & 15]);
    __syncthreads();

    int e = blockIdx.x;
    int c0 = blockIdx.y * 32;
    int off = expert_off[e];
    int cnt = expert_off[e + 1] - off;
    int col = c0 + (lane & 31);
    int q = lane >> 5;
    const int kbeg = wv * (NH / 4), kend = kbeg + (NH / 4);

    const size_t pkbase = (size_t)e * (NH / 2) * NI + col;
    const size_t scbase = (size_t)e * (NH / NGROUP) * NI + col;

    struct Buf { uint pg[8], pu[8]; bf16x8 xa[4]; float sg, su; };

    for (int s0 = blockIdx.z * 64; s0 < cnt; s0 += 192) {
        int r0 = s0 + (lane & 31), r1 = r0 + 32;
        int tk0 = (r0 < cnt) ? ptok[off + r0] : -1;
        int tk1 = (r1 < cnt) ? ptok[off + r1] : -1;
        const unsigned short* xp0 = xb + (size_t)tk0 * NH;
        const unsigned short* xp1 = xb + (size_t)tk1 * NH;

        f32x16 accg[2], accu[2];
        #pragma unroll
        for (int i = 0; i < 16; ++i) {
            accg[0][i] = 0.f; accg[1][i] = 0.f;
            accu[0][i] = 0.f; accu[1][i] = 0.f;
        }

        auto load = [&](Buf& B, int k0) {
            B.sg = gsc[scbase + (size_t)(k0 >> 6) * NI];
            B.su = usc[scbase + (size_t)(k0 >> 6) * NI];
            const int* gp_ = gpk + pkbase + (size_t)(k0 >> 1) * NI;
            const int* up_ = upk + pkbase + (size_t)(k0 >> 1) * NI;
            #pragma unroll
            for (int s = 0; s < 2; ++s) {
                int kk = k0 + s * 16 + q * 8;
                B.xa[s * 2 + 0] = (tk0 >= 0) ? *(const bf16x8*)(xp0 + kk) : bfzero();
                B.xa[s * 2 + 1] = (tk1 >= 0) ? *(const bf16x8*)(xp1 + kk) : bfzero();
                int rr = (s * 8 + q * 4) * NI;
                #pragma unroll
                for (int i = 0; i < 4; ++i) {
                    B.pg[s * 4 + i] = (uint)gp_[rr + i * NI];
                    B.pu[s * 4 + i] = (uint)up_[rr + i * NI];
                }
            }
        };
        auto comp = [&](Buf& B) {
            #pragma unroll
            for (int s = 0; s < 2; ++s) {
                uint4 wg4, wu4;
                uint* wg = &wg4.x; uint* wu = &wu4.x;
                #pragma unroll
                for (int i = 0; i < 4; ++i) {
                    float2 pg = ptab[B.pg[s * 4 + i] & 255];
                    float2 pu = ptab[B.pu[s * 4 + i] & 255];
                    wg[i] = bfpack2(pg.x * B.sg, pg.y * B.sg);
                    wu[i] = bfpack2(pu.x * B.su, pu.y * B.su);
                }
                bf16x8 bg = asbf(wg4), bu = asbf(wu4);
                accg[0] = MFMA32(B.xa[s * 2 + 0], bg, accg[0], 0, 0, 0);
                accg[1] = MFMA32(B.xa[s * 2 + 1], bg, accg[1], 0, 0, 0);
                accu[0] = MFMA32(B.xa[s * 2 + 0], bu, accu[0], 0, 0, 0);
                accu[1] = MFMA32(B.xa[s * 2 + 1], bu, accu[1], 0, 0, 0);
            }
        };

        Buf A, B;
        load(A, kbeg);
        for (int k0 = kbeg; k0 < kend; k0 += 64) {
            load(B, k0 + 32);
            comp(A);
            if (k0 + 64 < kend) load(A, k0 + 64);
            comp(B);
        }

        if (wv == 0) {
            // LoRA extension: += (x.A) . B  (K = 16)
            bf16x8 z = bfzero();
            bf16x8 ag0 = (r0 < cnt) ? *(const bf16x8*)(xAg + (size_t)(off + r0) * NR + q * 8) : z;
            bf16x8 ag1 = (r1 < cnt) ? *(const bf16x8*)(xAg + (size_t)(off + r1) * NR + q * 8) : z;
            bf16x8 au0 = (r0 < cnt) ? *(const bf16x8*)(xAu + (size_t)(off + r0) * NR + q * 8) : z;
            bf16x8 au1 = (r1 < cnt) ? *(const bf16x8*)(xAu + (size_t)(off + r1) * NR + q * 8) : z;
            const float* gq = gB + ((size_t)e * NR + q * 8) * NI + col;
            const float* uq = uB + ((size_t)e * NR + q * 8) * NI + col;
            uint4 wg4, wu4;
            uint* wg = &wg4.x; uint* wu = &wu4.x;
            #pragma unroll
            for (int i = 0; i < 4; ++i) {
                wg[i] = bfpack2(gq[(2 * i) * NI], gq[(2 * i + 1) * NI]);
                wu[i] = bfpack2(uq[(2 * i) * NI], uq[(2 * i + 1) * NI]);
            }
            bf16x8 bg = asbf(wg4), bu = asbf(wu4);
            accg[0] = MFMA32(ag0, bg, accg[0], 0, 0, 0);
            accg[1] = MFMA32(ag1, bg, accg[1], 0, 0, 0);
            accu[0] = MFMA32(au0, bu, accu[0], 0, 0, 0);
            accu[1] = MFMA32(au1, bu, accu[1], 0, 0, 0);
        } else {
            int w = wv - 1;
            #pragma unroll
            for (int mi = 0; mi < 2; ++mi)
                #pragma unroll
                for (int reg = 0; reg < 16; ++reg) {
                    red[w][0][mi][reg][lane] = accg[mi][reg];
                    red[w][1][mi][reg][lane] = accu[mi][reg];
                }
        }
        __syncthreads();
        if (wv == 0) {
            #pragma unroll
            for (int w = 0; w < 3; ++w)
                #pragma unroll
                for (int mi = 0; mi < 2; ++mi)
                    #pragma unroll
                    for (int reg = 0; reg < 16; ++reg) {
                        accg[mi][reg] += red[w][0][mi][reg][lane];
                        accu[mi][reg] += red[w][1][mi][reg][lane];
                    }
            // epilogue: SiLU(g)*u -> hbuf (bf16)
            int rb = 4 * q;
            #pragma unroll
            for (int mi = 0; mi < 2; ++mi)
                #pragma unroll
                for (int reg = 0; reg < 16; ++reg) {
                    int rloc = mi * 32 + rb + (reg & 3) + 8 * (reg >> 2);
                    if (s0 + rloc < cnt) {
                        float g = accg[mi][reg], u = accu[mi][reg];
                        float h = g * u / (1.f + __expf(-g));
                        hbuf[(size_t)(off + s0 + rloc) * NI + col] = (unsigned short)f2bf(h);
                    }
                }
        }
        __syncthreads();
    }
}

// -------- kernel 5: hA[p][r] = h . down_A (bf16 h in, bf16 out) --------
__global__ __launch_bounds__(256) void k_hA(const unsigned short* __restrict__ hbuf,
                                            const float* __restrict__ dA,
                                            const int* __restrict__ pexp,
                                            unsigned short* __restrict__ hA) {
    int p = blockIdx.x;
    int e = pexp[p];
    int tid = threadIdx.x;
    int r = tid & 15, ch = tid >> 4;   // 16 chunks of 64
    const unsigned short* hr = hbuf + (size_t)p * NI;
    const float* dAr = dA + (size_t)e * NI * NR;
    float sv = 0.f;
    for (int j = ch * 64; j < ch * 64 + 64; ++j) {
        float hv = __uint_as_float((uint)hr[j] << 16);
        sv += hv * dAr[j * NR + r];
    }
    __shared__ float red[16][16];
    red[ch][r] = sv;
    __syncthreads();
    for (int st = 8; st >= 1; st >>= 1) {
        if (ch < st) red[ch][r] += red[ch + st][r];
        __syncthreads();
    }
    if (tid < 16) hA[p * NR + tid] = (unsigned short)f2bf(red[0][tid]);
}

// -------- kernel 6: down GEMM, 4-wave K-split + LDS reduce + atomic combine --
__global__ __launch_bounds__(256) void k_down_mfma(
    const unsigned short* __restrict__ hbuf,
    const int* __restrict__ dpk, const float* __restrict__ dsc,
    const float* __restrict__ dB,
    const unsigned short* __restrict__ hA,
    const int* __restrict__ expert_off, const int* __restrict__ ptok,
    const float* __restrict__ pw,
    float* __restrict__ out)
{
    __shared__ float2 ptab[256];
    __shared__ float red[3][2][16][64];      // [wv-1][mi][reg][lane]
    int tid = threadIdx.x;
    int lane = tid & 63;
    int wv = tid >> 6;
    for (int i = tid; i < 256; i += 256)
        ptab[i] = make_float2(NF4_TAB[i & 15], NF4_TAB[(i >> 4) & 15]);
    __syncthreads();

    int e = blockIdx.x;
    int c0 = blockIdx.y * 32;
    int off = expert_off[e];
    int cnt = expert_off[e + 1] - off;
    int col = c0 + (lane & 31);
    int q = lane >> 5;
    const int kbeg = wv * (NI / 4), kend = kbeg + (NI / 4);

    const size_t pkbase = (size_t)e * (NI / 2) * NH + col;
    const size_t scbase = (size_t)e * (NI / NGROUP) * NH + col;

    struct Buf { uint pd[8]; bf16x8 ha[4]; float sc; };

    for (int s0 = blockIdx.z * 64; s0 < cnt; s0 += 192) {
        int r0 = s0 + (lane & 31), r1 = r0 + 32;
        bool v0 = r0 < cnt, v1 = r1 < cnt;
        const unsigned short* hp0 = hbuf + (size_t)(off + r0) * NI;
        const unsigned short* hp1 = hbuf + (size_t)(off + r1) * NI;

        f32x16 acc[2];
        #pragma unroll
        for (int i = 0; i < 16; ++i) { acc[0][i] = 0.f; acc[1][i] = 0.f; }

        auto load = [&](Buf& B, int k0) {
            B.sc = dsc[scbase + (size_t)(k0 >> 6) * NH];
            const int* dp = dpk + pkbase + (size_t)(k0 >> 1) * NH;
            #pragma unroll
            for (int s = 0; s < 2; ++s) {
                int kk = k0 + s * 16 + q * 8;
                B.ha[s * 2 + 0] = v0 ? *(const bf16x8*)(hp0 + kk) : bfzero();
                B.ha[s * 2 + 1] = v1 ? *(const bf16x8*)(hp1 + kk) : bfzero();
                int rr = (s * 8 + q * 4) * NH;
                #pragma unroll
                for (int i = 0; i < 4; ++i)
                    B.pd[s * 4 + i] = (uint)dp[rr + i * NH];
            }
        };
        auto comp = [&](Buf& B) {
            #pragma unroll
            for (int s = 0; s < 2; ++s) {
                uint4 w4;
                uint* w = &w4.x;
                #pragma unroll
                for (int i = 0; i < 4; ++i) {
                    float2 pv = ptab[B.pd[s * 4 + i] & 255];
                    w[i] = bfpack2(pv.x * B.sc, pv.y * B.sc);
                }
                bf16x8 b = asbf(w4);
                acc[0] = MFMA32(B.ha[s * 2 + 0], b, acc[0], 0, 0, 0);
                acc[1] = MFMA32(B.ha[s * 2 + 1], b, acc[1], 0, 0, 0);
            }
        };

        Buf A, B;
        load(A, kbeg);
        for (int k0 = kbeg; k0 < kend; k0 += 64) {
            load(B, k0 + 32);
            comp(A);
            if (k0 + 64 < kend) load(A, k0 + 64);
            comp(B);
        }

        if (wv == 0) {
            // LoRA extension: += (h.down_A) . down_B (K = 16)
            bf16x8 z = bfzero();
            bf16x8 a0 = v0 ? *(const bf16x8*)(hA + (size_t)(off + r0) * NR + q * 8) : z;
            bf16x8 a1 = v1 ? *(const bf16x8*)(hA + (size_t)(off + r1) * NR + q * 8) : z;
            const float* dq_ = dB + ((size_t)e * NR + q * 8) * NH + col;
            uint4 w4;
            uint* w = &w4.x;
            #pragma unroll
            for (int i = 0; i < 4; ++i)
                w[i] = bfpack2(dq_[(2 * i) * NH], dq_[(2 * i + 1) * NH]);
            bf16x8 b = asbf(w4);
            acc[0] = MFMA32(a0, b, acc[0], 0, 0, 0);
            acc[1] = MFMA32(a1, b, acc[1], 0, 0, 0);
        } else {
            int w = wv - 1;
            #pragma unroll
            for (int mi = 0; mi < 2; ++mi)
                #pragma unroll
                for (int reg = 0; reg < 16; ++reg)
                    red[w][mi][reg][lane] = acc[mi][reg];
        }
        __syncthreads();
        if (wv == 0) {
            #pragma unroll
            for (int w = 0; w < 3; ++w)
                #pragma unroll
                for (int mi = 0; mi < 2; ++mi)
                    #pragma unroll
                    for (int reg = 0; reg < 16; ++reg)
                        acc[mi][reg] += red[w][mi][reg][lane];
            // epilogue: weighted atomic combine into out
            int rb = 4 * q;
            #pragma unroll
            for (int mi = 0; mi < 2; ++mi)
                #pragma unroll
                for (int reg = 0; reg < 16; ++reg) {
                    int rloc = mi * 32 + rb + (reg & 3) + 8 * (reg >> 2);
                    if (s0 + rloc < cnt) {
                        int p = off + s0 + rloc;
                        float v = acc[mi][reg] * pw[p];
                        atomicAdd(&out[(size_t)ptok[p] * NH + col], v);
                    }
                }
        }
        __syncthreads();
    }
}

extern "C" void kernel_launch(void* const* d_in, const int* in_sizes, int n_in,
                              void* d_out, int out_size, void* d_ws,
                              size_t ws_size, hipStream_t stream) {
    const float* x = (const float*)d_in[0];
    const int* topk_idx = (const int*)d_in[1];
    const float* topk_w = (const float*)d_in[2];
    const int* gate_packed = (const int*)d_in[3];
    const float* gate_scales = (const float*)d_in[4];
    const int* up_packed = (const int*)d_in[5];
    const float* up_scales = (const float*)d_in[6];
    const int* down_packed = (const int*)d_in[7];
    const float* down_scales = (const float*)d_in[8];
    const float* gate_A = (const float*)d_in[9];
    const float* gate_B = (const float*)d_in[10];
    const float* up_A = (const float*)d_in[11];
    const float* up_B = (const float*)d_in[12];
    const float* down_A = (const float*)d_in[13];
    const float* down_B = (const float*)d_in[14];
    float* out = (float*)d_out;

    char* ws = (char*)d_ws;
    int* expert_off = (int*)(ws + OFF_EXPOFF);
    int* ptok = (int*)(ws + OFF_TOK);
    int* pexp = (int*)(ws + OFF_EXP);
    float* pw = (float*)(ws + OFF_W);
    unsigned short* xAg = (unsigned short*)(ws + OFF_XAG);
    unsigned short* xAu = (unsigned short*)(ws + OFF_XAU);
    unsigned short* hA = (unsigned short*)(ws + OFF_HA);
    unsigned short* xb = (unsigned short*)(ws + OFF_XB);
    unsigned short* hbuf = (unsigned short*)(ws + OFF_HBUF);

    hipMemsetAsync(d_out, 0, (size_t)NT * NH * sizeof(float), stream);

    k_route<<<1, 1024, 0, stream>>>(topk_idx, topk_w, expert_off, ptok, pexp, pw);
    k_xcvt<<<(NT * NH) / (256 * 8), 256, 0, stream>>>(x, xb);
    k_xA<<<NPAIR, 256, 0, stream>>>(x, gate_A, up_A, ptok, pexp, xAg, xAu);
    k_gateup_mfma<<<dim3(NE, NI / 32, 3), 256, 0, stream>>>(
        xb, gate_packed, gate_scales, up_packed, up_scales, gate_B, up_B,
        xAg, xAu, expert_off, ptok, hbuf);
    k_hA<<<NPAIR, 256, 0, stream>>>(hbuf, down_A, pexp, hA);
    k_down_mfma<<<dim3(NE, NH / 32, 3), 256, 0, stream>>>(
        hbuf, down_packed, down_scales, down_B, hA, expert_off, ptok, pw, out);
}